// Round 4
// baseline (922.768 us; speedup 1.0000x reference)
//
#include <hip/hip_runtime.h>

#define NODES_MAX 100000
#define EDGES_MAX 1600000
#define BN 256                                   // nodes per bucket (pow2)
#define NBUCK ((NODES_MAX + BN - 1) / BN)        // 391

// Float scratch: N*256 floats @ N=100000 -> 102.4 MB
// layout (float offsets): t1:0  r1:N*32  h1:N*64  t2:N*96  r2:N*144  h2:N*192  t3:N*240
__device__ float g_ws[(size_t)NODES_MAX * 256];
__device__ int g_rowptr[NODES_MAX + 1];
__device__ int g_csr[EDGES_MAX];          // src ids grouped by dst
__device__ unsigned g_be[EDGES_MAX];      // bucket-ordered packed (src<<8)|local_dst
__device__ int g_bcnt[NBUCK + 1];
__device__ int g_boff[NBUCK + 1];
__device__ int g_bcur[NBUCK];

// ---------------- CSR build (bucketed two-phase) ----------------
__global__ __launch_bounds__(512) void k_zero_bcnt(int nbuck) {
    int i = threadIdx.x;
    if (i <= nbuck) g_bcnt[i] = 0;
}

// Per-block LDS histogram of buckets, then one global atomic per (block,bucket).
__global__ __launch_bounds__(1024) void k_bcount(const int* __restrict__ edge, int E, int nbuck) {
    __shared__ int h[NBUCK];
    for (int i = threadIdx.x; i < nbuck; i += 1024) h[i] = 0;
    __syncthreads();
    for (int e = blockIdx.x * 1024 + threadIdx.x; e < E; e += gridDim.x * 1024)
        atomicAdd(&h[edge[E + e] >> 8], 1);
    __syncthreads();
    for (int i = threadIdx.x; i < nbuck; i += 1024) {
        int v = h[i];
        if (v) atomicAdd(&g_bcnt[i], v);
    }
}

// Exclusive scan of bucket counts (nbuck <= 512), init cursors.
__global__ __launch_bounds__(512) void k_bscan(int nbuck, int E) {
    __shared__ int s[512];
    const int tid = threadIdx.x;
    int v = (tid < nbuck) ? g_bcnt[tid] : 0;
    s[tid] = v;
    __syncthreads();
    for (int off = 1; off < 512; off <<= 1) {
        int t = (tid >= off) ? s[tid - off] : 0;
        __syncthreads();
        s[tid] += t;
        __syncthreads();
    }
    if (tid < nbuck) {
        int excl = s[tid] - v;
        g_boff[tid] = excl;
        g_bcur[tid] = excl;
    }
    if (tid == 0) g_boff[nbuck] = E;
}

// Scatter edges into bucket-ordered packed array (writes sequential per bucket).
__global__ __launch_bounds__(256) void k_bscatter(const int* __restrict__ edge, int E) {
    int e = blockIdx.x * 256 + threadIdx.x;
    if (e < E) {
        int s = edge[e], d = edge[E + e];
        int pos = atomicAdd(&g_bcur[d >> 8], 1);
        g_be[pos] = ((unsigned)s << 8) | (unsigned)(d & (BN - 1));
    }
}

// One workgroup per bucket: LDS hist of 256 local nodes + LDS scan -> rowptr,
// then scatter srcs into the bucket's contiguous CSR slice (LDS cursors).
__global__ __launch_bounds__(BN) void k_csr(int N, int E) {
    const int b = blockIdx.x;
    const int nlo = b * BN;
    const int ebase = g_boff[b], eend = g_boff[b + 1];
    __shared__ int cnt[BN];
    __shared__ int pfx[BN];
    const int tid = threadIdx.x;
    cnt[tid] = 0;
    __syncthreads();
    for (int e = ebase + tid; e < eend; e += BN)
        atomicAdd(&cnt[g_be[e] & (BN - 1)], 1);
    __syncthreads();
    int v = cnt[tid];
    pfx[tid] = v;
    __syncthreads();
    for (int off = 1; off < BN; off <<= 1) {
        int t = (tid >= off) ? pfx[tid - off] : 0;
        __syncthreads();
        pfx[tid] += t;
        __syncthreads();
    }
    int excl = pfx[tid] - v;
    int n = nlo + tid;
    if (n < N) g_rowptr[n] = ebase + excl;
    if (b == 0 && tid == 0) g_rowptr[N] = E;
    cnt[tid] = excl;  // reuse as cursor
    __syncthreads();
    for (int e = ebase + tid; e < eend; e += BN) {
        unsigned pv = g_be[e];
        int pos = atomicAdd(&cnt[pv & (BN - 1)], 1);
        g_csr[ebase + pos] = (int)(pv >> 8);
    }
}

// ---------------- gathers ----------------
// h[node] = relu( sum_{in-edges} t[src] + r[node] )
template <int F>
__global__ __launch_bounds__(256) void k_gather_relu(size_t oT, size_t oR, size_t oH, int N) {
    constexpr int F4 = F / 4;
    int tid = blockIdx.x * 256 + threadIdx.x;
    int node = tid / F4, c4 = tid % F4;
    if (node >= N) return;
    const float* __restrict__ t = &g_ws[oT];
    int start = g_rowptr[node], end = g_rowptr[node + 1];
    float4 s = {0.f, 0.f, 0.f, 0.f};
    for (int j = start; j < end; ++j) {
        int sn = g_csr[j];
        const float4 v = *(const float4*)&t[(size_t)sn * F + c4 * 4];
        s.x += v.x; s.y += v.y; s.z += v.z; s.w += v.w;
    }
    const float4 rv = *(const float4*)&g_ws[oR + (size_t)node * F + c4 * 4];
    float4 o;
    o.x = fmaxf(s.x + rv.x, 0.f);
    o.y = fmaxf(s.y + rv.y, 0.f);
    o.z = fmaxf(s.z + rv.z, 0.f);
    o.w = fmaxf(s.w + rv.w, 0.f);
    *(float4*)&g_ws[oH + (size_t)node * F + c4 * 4] = o;
}

// out[node] += sum_{in-edges} t3[src]   (out pre-seeded with root+bias+ax)
__global__ __launch_bounds__(256) void k_gather_out(size_t oT, float* __restrict__ out, int N) {
    constexpr int F = 16, F4 = 4;
    int tid = blockIdx.x * 256 + threadIdx.x;
    int node = tid / F4, c4 = tid % F4;
    if (node >= N) return;
    const float* __restrict__ t = &g_ws[oT];
    int start = g_rowptr[node], end = g_rowptr[node + 1];
    float4 s = {0.f, 0.f, 0.f, 0.f};
    for (int j = start; j < end; ++j) {
        int sn = g_csr[j];
        const float4 v = *(const float4*)&t[(size_t)sn * F + c4 * 4];
        s.x += v.x; s.y += v.y; s.z += v.z; s.w += v.w;
    }
    float4* op = (float4*)&out[(size_t)node * F + c4 * 4];
    float4 ov = *op;
    ov.x += s.x; ov.y += s.y; ov.z += s.z; ov.w += s.w;
    *op = ov;
}

// ---------------- transforms ----------------
__global__ __launch_bounds__(256) void k_l1_transform(
        const float* __restrict__ x, const float* __restrict__ ax,
        const float* __restrict__ Wrel, const float* __restrict__ Wroot,
        const float* __restrict__ b, int N, size_t oT1, size_t oR1) {
    __shared__ float sWrel[64 * 32];
    __shared__ float sWroot[64 * 32];
    __shared__ float sH[8 * 64];
    const int tid = threadIdx.x;
    for (int i = tid; i < 64 * 32; i += 256) { sWrel[i] = Wrel[i]; sWroot[i] = Wroot[i]; }
    const int n0 = blockIdx.x * 8;
    for (int i = tid; i < 8 * 64; i += 256) {
        int nl = i >> 6, k = i & 63, n = n0 + nl;
        float v = 0.f;
        if (n < N) v = (k < 48) ? x[(size_t)n * 48 + k] : ax[(size_t)n * 16 + (k - 48)];
        sH[i] = v;
    }
    __syncthreads();
    const int nl = tid >> 5, j = tid & 31, n = n0 + nl;
    if (n < N) {
        float at = 0.f, ar = 0.f;
        #pragma unroll
        for (int k = 0; k < 64; ++k) {
            float h = sH[nl * 64 + k];
            at = fmaf(h, sWrel[k * 32 + j], at);
            ar = fmaf(h, sWroot[k * 32 + j], ar);
        }
        g_ws[oT1 + (size_t)n * 32 + j] = at;
        g_ws[oR1 + (size_t)n * 32 + j] = ar + b[j];
    }
}

__global__ __launch_bounds__(384) void k_l2_transform(
        const float* __restrict__ lf,
        const float* __restrict__ Wrel, const float* __restrict__ Wroot,
        const float* __restrict__ b, int N,
        size_t oH1, size_t oT2, size_t oR2) {
    __shared__ float sWrel[48 * 48];
    __shared__ float sWroot[48 * 48];
    __shared__ float sH[8 * 48];
    const int tid = threadIdx.x;
    for (int i = tid; i < 48 * 48; i += 384) { sWrel[i] = Wrel[i]; sWroot[i] = Wroot[i]; }
    const int n0 = blockIdx.x * 8;
    {
        int nl = tid / 48, k = tid % 48, n = n0 + nl;  // 384 == 8*48
        float v = 0.f;
        if (n < N) {
            v = (k < 32) ? g_ws[oH1 + (size_t)n * 32 + k]
                         : lf[(size_t)n * 16 + (k - 32)];
        }
        sH[tid] = v;
    }
    __syncthreads();
    const int nl = tid / 48, j = tid % 48, n = n0 + nl;
    if (n < N) {
        float at = 0.f, ar = 0.f;
        #pragma unroll
        for (int k = 0; k < 48; ++k) {
            float h = sH[nl * 48 + k];
            at = fmaf(h, sWrel[k * 48 + j], at);
            ar = fmaf(h, sWroot[k * 48 + j], ar);
        }
        g_ws[oT2 + (size_t)n * 48 + j] = at;
        g_ws[oR2 + (size_t)n * 48 + j] = ar + b[j];
    }
}

__global__ __launch_bounds__(256) void k_l3_transform(
        const float* __restrict__ ax,
        const float* __restrict__ Wrel, const float* __restrict__ Wroot,
        const float* __restrict__ b, int N,
        size_t oH2, size_t oT3, float* __restrict__ out) {
    __shared__ float sWrel[48 * 16];
    __shared__ float sWroot[48 * 16];
    __shared__ float sH[16 * 48];
    const int tid = threadIdx.x;
    for (int i = tid; i < 48 * 16; i += 256) { sWrel[i] = Wrel[i]; sWroot[i] = Wroot[i]; }
    const int n0 = blockIdx.x * 16;
    for (int i = tid; i < 16 * 48; i += 256) {
        int nl = i / 48, k = i % 48, n = n0 + nl;
        sH[i] = (n < N) ? g_ws[oH2 + (size_t)n * 48 + k] : 0.f;
    }
    __syncthreads();
    const int nl = tid >> 4, j = tid & 15, n = n0 + nl;
    if (n < N) {
        float at = 0.f, ar = 0.f;
        #pragma unroll
        for (int k = 0; k < 48; ++k) {
            float h = sH[nl * 48 + k];
            at = fmaf(h, sWrel[k * 16 + j], at);
            ar = fmaf(h, sWroot[k * 16 + j], ar);
        }
        g_ws[oT3 + (size_t)n * 16 + j] = at;
        out[(size_t)n * 16 + j] = ar + b[j] + ax[(size_t)n * 16 + j];
    }
}

extern "C" void kernel_launch(void* const* d_in, const int* in_sizes, int n_in,
                              void* d_out, int out_size, void* d_ws, size_t ws_size,
                              hipStream_t stream) {
    const float* x     = (const float*)d_in[0];
    const int*   edge  = (const int*)d_in[1];
    const float* ax    = (const float*)d_in[2];
    const float* lf    = (const float*)d_in[3];
    const float* W1rel = (const float*)d_in[4];
    const float* b1    = (const float*)d_in[5];
    const float* W1root= (const float*)d_in[6];
    const float* W2rel = (const float*)d_in[7];
    const float* b2    = (const float*)d_in[8];
    const float* W2root= (const float*)d_in[9];
    const float* W3rel = (const float*)d_in[10];
    const float* b3    = (const float*)d_in[11];
    const float* W3root= (const float*)d_in[12];
    float* out = (float*)d_out;

    const int N = in_sizes[0] / 48;
    const int E = in_sizes[1] / 2;
    const int nbuck = (N + BN - 1) / BN;

    const size_t oT1 = 0;
    const size_t oR1 = (size_t)N * 32;
    const size_t oH1 = (size_t)N * 64;
    const size_t oT2 = (size_t)N * 96;
    const size_t oR2 = (size_t)N * 144;
    const size_t oH2 = (size_t)N * 192;
    const size_t oT3 = (size_t)N * 240;

    const int eb = (E + 255) / 256;

    // CSR build (bucketed two-phase)
    k_zero_bcnt<<<1, 512, 0, stream>>>(nbuck);
    k_bcount<<<256, 1024, 0, stream>>>(edge, E, nbuck);
    k_bscan<<<1, 512, 0, stream>>>(nbuck, E);
    k_bscatter<<<eb, 256, 0, stream>>>(edge, E);
    k_csr<<<nbuck, BN, 0, stream>>>(N, E);

    // Layer 1
    k_l1_transform<<<(N + 7) / 8, 256, 0, stream>>>(x, ax, W1rel, W1root, b1, N, oT1, oR1);
    k_gather_relu<32><<<(unsigned)(((size_t)N * 8 + 255) / 256), 256, 0, stream>>>(oT1, oR1, oH1, N);
    // Layer 2
    k_l2_transform<<<(N + 7) / 8, 384, 0, stream>>>(lf, W2rel, W2root, b2, N, oH1, oT2, oR2);
    k_gather_relu<48><<<(unsigned)(((size_t)N * 12 + 255) / 256), 256, 0, stream>>>(oT2, oR2, oH2, N);
    // Layer 3
    k_l3_transform<<<(N + 15) / 16, 256, 0, stream>>>(ax, W3rel, W3root, b3, N, oH2, oT3, out);
    k_gather_out<<<(unsigned)(((size_t)N * 4 + 255) / 256), 256, 0, stream>>>(oT3, out, N);
}

// Round 5
// 377.999 us; speedup vs baseline: 2.4412x; 2.4412x over previous
//
#include <hip/hip_runtime.h>

#define NODES_MAX 100000
#define EDGES_MAX 1600000
#define BN 256                                   // nodes per bucket (pow2)
#define NBUCK ((NODES_MAX + BN - 1) / BN)        // 391
#define B_PART 256                               // partition blocks (fixed)
#define SCAN_CHUNK 1024

// Float scratch: N*256 floats @ N=100000 -> 102.4 MB
// layout (float offsets): t1:0  r1:N*32  h1:N*64  t2:N*96  r2:N*144  h2:N*192  t3:N*240
__device__ float g_ws[(size_t)NODES_MAX * 256];
__device__ int g_rowptr[NODES_MAX + 1];
__device__ int g_csr[EDGES_MAX];            // src ids grouped by dst
__device__ unsigned g_be[EDGES_MAX];        // bucket-ordered packed (src<<8)|local_dst
__device__ int g_mat[NBUCK * B_PART];       // per-(bucket,block) counts -> offsets
__device__ int g_boff[NBUCK + 1];           // bucket base offsets
__device__ int g_bsum[(NBUCK * B_PART + SCAN_CHUNK - 1) / SCAN_CHUNK + 1];

// ---------------- CSR build (radix partition, no global atomics) ----------------
// Phase 1: per-block LDS histogram of its contiguous edge chunk.
__global__ __launch_bounds__(1024) void k_bcount(const int* __restrict__ edge, int E,
                                                 int nbuck, int chunk) {
    __shared__ int h[NBUCK];
    for (int i = threadIdx.x; i < nbuck; i += 1024) h[i] = 0;
    __syncthreads();
    const int lo = blockIdx.x * chunk, hi = min(E, lo + chunk);
    for (int e = lo + threadIdx.x; e < hi; e += 1024)
        atomicAdd(&h[edge[E + e] >> 8], 1);
    __syncthreads();
    for (int k = threadIdx.x; k < nbuck; k += 1024)
        g_mat[k * B_PART + blockIdx.x] = h[k];
}

// Multi-block exclusive scan over g_mat (M = nbuck*B_PART elements), in place.
__global__ __launch_bounds__(256) void k_scan_local(int M) {
    __shared__ int ssum[256];
    const int tid = threadIdx.x;
    const int base = blockIdx.x * SCAN_CHUNK + tid * 4;
    int v0 = (base + 0 < M) ? g_mat[base + 0] : 0;
    int v1 = (base + 1 < M) ? g_mat[base + 1] : 0;
    int v2 = (base + 2 < M) ? g_mat[base + 2] : 0;
    int v3 = (base + 3 < M) ? g_mat[base + 3] : 0;
    int s = v0 + v1 + v2 + v3;
    ssum[tid] = s;
    __syncthreads();
    for (int off = 1; off < 256; off <<= 1) {
        int v = (tid >= off) ? ssum[tid - off] : 0;
        __syncthreads();
        ssum[tid] += v;
        __syncthreads();
    }
    int run = ssum[tid] - s;
    if (base + 0 < M) g_mat[base + 0] = run;
    run += v0;
    if (base + 1 < M) g_mat[base + 1] = run;
    run += v1;
    if (base + 2 < M) g_mat[base + 2] = run;
    run += v2;
    if (base + 3 < M) g_mat[base + 3] = run;
    if (tid == 255) g_bsum[blockIdx.x] = ssum[255];
}

__global__ __launch_bounds__(1024) void k_scan_bsums(int nb) {
    __shared__ int ssum[1024];
    const int tid = threadIdx.x;
    int s = (tid < nb) ? g_bsum[tid] : 0;
    ssum[tid] = s;
    __syncthreads();
    for (int off = 1; off < 1024; off <<= 1) {
        int v = (tid >= off) ? ssum[tid - off] : 0;
        __syncthreads();
        ssum[tid] += v;
        __syncthreads();
    }
    if (tid < nb) g_bsum[tid] = ssum[tid] - s;
}

__global__ __launch_bounds__(256) void k_scan_add(int M, int nbuck, int E) {
    int i = blockIdx.x * 256 + threadIdx.x;
    if (i < M) {
        int v = g_mat[i] + g_bsum[i / SCAN_CHUNK];
        g_mat[i] = v;
        if ((i & (B_PART - 1)) == 0) g_boff[i / B_PART] = v;  // bucket base
    }
    if (i == 0) g_boff[nbuck] = E;
}

// Phase 3: re-read chunk, rank via LDS cursors, write to private sub-ranges.
__global__ __launch_bounds__(1024) void k_bpart(const int* __restrict__ edge, int E,
                                                int nbuck, int chunk) {
    __shared__ int cur[NBUCK];
    for (int k = threadIdx.x; k < nbuck; k += 1024)
        cur[k] = g_mat[k * B_PART + blockIdx.x];
    __syncthreads();
    const int lo = blockIdx.x * chunk, hi = min(E, lo + chunk);
    for (int e = lo + threadIdx.x; e < hi; e += 1024) {
        int s = edge[e], d = edge[E + e];
        int pos = atomicAdd(&cur[d >> 8], 1);
        g_be[pos] = ((unsigned)s << 8) | (unsigned)(d & (BN - 1));
    }
}

// One workgroup per bucket: LDS hist of 256 local nodes + LDS scan -> rowptr,
// then scatter srcs into the bucket's contiguous CSR slice (LDS cursors).
__global__ __launch_bounds__(BN) void k_csr(int N, int E) {
    const int b = blockIdx.x;
    const int nlo = b * BN;
    const int ebase = g_boff[b], eend = g_boff[b + 1];
    __shared__ int cnt[BN];
    __shared__ int pfx[BN];
    const int tid = threadIdx.x;
    cnt[tid] = 0;
    __syncthreads();
    for (int e = ebase + tid; e < eend; e += BN)
        atomicAdd(&cnt[g_be[e] & (BN - 1)], 1);
    __syncthreads();
    int v = cnt[tid];
    pfx[tid] = v;
    __syncthreads();
    for (int off = 1; off < BN; off <<= 1) {
        int t = (tid >= off) ? pfx[tid - off] : 0;
        __syncthreads();
        pfx[tid] += t;
        __syncthreads();
    }
    int excl = pfx[tid] - v;
    int n = nlo + tid;
    if (n < N) g_rowptr[n] = ebase + excl;
    if (b == 0 && tid == 0) g_rowptr[N] = E;
    cnt[tid] = excl;  // reuse as cursor
    __syncthreads();
    for (int e = ebase + tid; e < eend; e += BN) {
        unsigned pv = g_be[e];
        int pos = atomicAdd(&cnt[pv & (BN - 1)], 1);
        g_csr[ebase + pos] = (int)(pv >> 8);
    }
}

// ---------------- gathers ----------------
// h[node] = relu( sum_{in-edges} t[src] + r[node] )
template <int F>
__global__ __launch_bounds__(256) void k_gather_relu(size_t oT, size_t oR, size_t oH, int N) {
    constexpr int F4 = F / 4;
    int tid = blockIdx.x * 256 + threadIdx.x;
    int node = tid / F4, c4 = tid % F4;
    if (node >= N) return;
    const float* __restrict__ t = &g_ws[oT];
    int start = g_rowptr[node], end = g_rowptr[node + 1];
    float4 s = {0.f, 0.f, 0.f, 0.f};
    for (int j = start; j < end; ++j) {
        int sn = g_csr[j];
        const float4 v = *(const float4*)&t[(size_t)sn * F + c4 * 4];
        s.x += v.x; s.y += v.y; s.z += v.z; s.w += v.w;
    }
    const float4 rv = *(const float4*)&g_ws[oR + (size_t)node * F + c4 * 4];
    float4 o;
    o.x = fmaxf(s.x + rv.x, 0.f);
    o.y = fmaxf(s.y + rv.y, 0.f);
    o.z = fmaxf(s.z + rv.z, 0.f);
    o.w = fmaxf(s.w + rv.w, 0.f);
    *(float4*)&g_ws[oH + (size_t)node * F + c4 * 4] = o;
}

// out[node] += sum_{in-edges} t3[src]   (out pre-seeded with root+bias+ax)
__global__ __launch_bounds__(256) void k_gather_out(size_t oT, float* __restrict__ out, int N) {
    constexpr int F = 16, F4 = 4;
    int tid = blockIdx.x * 256 + threadIdx.x;
    int node = tid / F4, c4 = tid % F4;
    if (node >= N) return;
    const float* __restrict__ t = &g_ws[oT];
    int start = g_rowptr[node], end = g_rowptr[node + 1];
    float4 s = {0.f, 0.f, 0.f, 0.f};
    for (int j = start; j < end; ++j) {
        int sn = g_csr[j];
        const float4 v = *(const float4*)&t[(size_t)sn * F + c4 * 4];
        s.x += v.x; s.y += v.y; s.z += v.z; s.w += v.w;
    }
    float4* op = (float4*)&out[(size_t)node * F + c4 * 4];
    float4 ov = *op;
    ov.x += s.x; ov.y += s.y; ov.z += s.z; ov.w += s.w;
    *op = ov;
}

// ---------------- transforms ----------------
__global__ __launch_bounds__(256) void k_l1_transform(
        const float* __restrict__ x, const float* __restrict__ ax,
        const float* __restrict__ Wrel, const float* __restrict__ Wroot,
        const float* __restrict__ b, int N, size_t oT1, size_t oR1) {
    __shared__ float sWrel[64 * 32];
    __shared__ float sWroot[64 * 32];
    __shared__ float sH[8 * 64];
    const int tid = threadIdx.x;
    for (int i = tid; i < 64 * 32; i += 256) { sWrel[i] = Wrel[i]; sWroot[i] = Wroot[i]; }
    const int n0 = blockIdx.x * 8;
    for (int i = tid; i < 8 * 64; i += 256) {
        int nl = i >> 6, k = i & 63, n = n0 + nl;
        float v = 0.f;
        if (n < N) v = (k < 48) ? x[(size_t)n * 48 + k] : ax[(size_t)n * 16 + (k - 48)];
        sH[i] = v;
    }
    __syncthreads();
    const int nl = tid >> 5, j = tid & 31, n = n0 + nl;
    if (n < N) {
        float at = 0.f, ar = 0.f;
        #pragma unroll
        for (int k = 0; k < 64; ++k) {
            float h = sH[nl * 64 + k];
            at = fmaf(h, sWrel[k * 32 + j], at);
            ar = fmaf(h, sWroot[k * 32 + j], ar);
        }
        g_ws[oT1 + (size_t)n * 32 + j] = at;
        g_ws[oR1 + (size_t)n * 32 + j] = ar + b[j];
    }
}

__global__ __launch_bounds__(384) void k_l2_transform(
        const float* __restrict__ lf,
        const float* __restrict__ Wrel, const float* __restrict__ Wroot,
        const float* __restrict__ b, int N,
        size_t oH1, size_t oT2, size_t oR2) {
    __shared__ float sWrel[48 * 48];
    __shared__ float sWroot[48 * 48];
    __shared__ float sH[8 * 48];
    const int tid = threadIdx.x;
    for (int i = tid; i < 48 * 48; i += 384) { sWrel[i] = Wrel[i]; sWroot[i] = Wroot[i]; }
    const int n0 = blockIdx.x * 8;
    {
        int nl = tid / 48, k = tid % 48, n = n0 + nl;  // 384 == 8*48
        float v = 0.f;
        if (n < N) {
            v = (k < 32) ? g_ws[oH1 + (size_t)n * 32 + k]
                         : lf[(size_t)n * 16 + (k - 32)];
        }
        sH[tid] = v;
    }
    __syncthreads();
    const int nl = tid / 48, j = tid % 48, n = n0 + nl;
    if (n < N) {
        float at = 0.f, ar = 0.f;
        #pragma unroll
        for (int k = 0; k < 48; ++k) {
            float h = sH[nl * 48 + k];
            at = fmaf(h, sWrel[k * 48 + j], at);
            ar = fmaf(h, sWroot[k * 48 + j], ar);
        }
        g_ws[oT2 + (size_t)n * 48 + j] = at;
        g_ws[oR2 + (size_t)n * 48 + j] = ar + b[j];
    }
}

__global__ __launch_bounds__(256) void k_l3_transform(
        const float* __restrict__ ax,
        const float* __restrict__ Wrel, const float* __restrict__ Wroot,
        const float* __restrict__ b, int N,
        size_t oH2, size_t oT3, float* __restrict__ out) {
    __shared__ float sWrel[48 * 16];
    __shared__ float sWroot[48 * 16];
    __shared__ float sH[16 * 48];
    const int tid = threadIdx.x;
    for (int i = tid; i < 48 * 16; i += 256) { sWrel[i] = Wrel[i]; sWroot[i] = Wroot[i]; }
    const int n0 = blockIdx.x * 16;
    for (int i = tid; i < 16 * 48; i += 256) {
        int nl = i / 48, k = i % 48, n = n0 + nl;
        sH[i] = (n < N) ? g_ws[oH2 + (size_t)n * 48 + k] : 0.f;
    }
    __syncthreads();
    const int nl = tid >> 4, j = tid & 15, n = n0 + nl;
    if (n < N) {
        float at = 0.f, ar = 0.f;
        #pragma unroll
        for (int k = 0; k < 48; ++k) {
            float h = sH[nl * 48 + k];
            at = fmaf(h, sWrel[k * 16 + j], at);
            ar = fmaf(h, sWroot[k * 16 + j], ar);
        }
        g_ws[oT3 + (size_t)n * 16 + j] = at;
        out[(size_t)n * 16 + j] = ar + b[j] + ax[(size_t)n * 16 + j];
    }
}

extern "C" void kernel_launch(void* const* d_in, const int* in_sizes, int n_in,
                              void* d_out, int out_size, void* d_ws, size_t ws_size,
                              hipStream_t stream) {
    const float* x     = (const float*)d_in[0];
    const int*   edge  = (const int*)d_in[1];
    const float* ax    = (const float*)d_in[2];
    const float* lf    = (const float*)d_in[3];
    const float* W1rel = (const float*)d_in[4];
    const float* b1    = (const float*)d_in[5];
    const float* W1root= (const float*)d_in[6];
    const float* W2rel = (const float*)d_in[7];
    const float* b2    = (const float*)d_in[8];
    const float* W2root= (const float*)d_in[9];
    const float* W3rel = (const float*)d_in[10];
    const float* b3    = (const float*)d_in[11];
    const float* W3root= (const float*)d_in[12];
    float* out = (float*)d_out;

    const int N = in_sizes[0] / 48;
    const int E = in_sizes[1] / 2;
    const int nbuck = (N + BN - 1) / BN;
    const int chunk = (E + B_PART - 1) / B_PART;
    const int M = nbuck * B_PART;
    const int nb = (M + SCAN_CHUNK - 1) / SCAN_CHUNK;

    const size_t oT1 = 0;
    const size_t oR1 = (size_t)N * 32;
    const size_t oH1 = (size_t)N * 64;
    const size_t oT2 = (size_t)N * 96;
    const size_t oR2 = (size_t)N * 144;
    const size_t oH2 = (size_t)N * 192;
    const size_t oT3 = (size_t)N * 240;

    // CSR build (radix partition, no global atomics)
    k_bcount<<<B_PART, 1024, 0, stream>>>(edge, E, nbuck, chunk);
    k_scan_local<<<nb, 256, 0, stream>>>(M);
    k_scan_bsums<<<1, 1024, 0, stream>>>(nb);
    k_scan_add<<<(M + 255) / 256, 256, 0, stream>>>(M, nbuck, E);
    k_bpart<<<B_PART, 1024, 0, stream>>>(edge, E, nbuck, chunk);
    k_csr<<<nbuck, BN, 0, stream>>>(N, E);

    // Layer 1
    k_l1_transform<<<(N + 7) / 8, 256, 0, stream>>>(x, ax, W1rel, W1root, b1, N, oT1, oR1);
    k_gather_relu<32><<<(unsigned)(((size_t)N * 8 + 255) / 256), 256, 0, stream>>>(oT1, oR1, oH1, N);
    // Layer 2
    k_l2_transform<<<(N + 7) / 8, 384, 0, stream>>>(lf, W2rel, W2root, b2, N, oH1, oT2, oR2);
    k_gather_relu<48><<<(unsigned)(((size_t)N * 12 + 255) / 256), 256, 0, stream>>>(oT2, oR2, oH2, N);
    // Layer 3
    k_l3_transform<<<(N + 15) / 16, 256, 0, stream>>>(ax, W3rel, W3root, b3, N, oH2, oT3, out);
    k_gather_out<<<(unsigned)(((size_t)N * 4 + 255) / 256), 256, 0, stream>>>(oT3, out, N);
}

// Round 6
// 365.361 us; speedup vs baseline: 2.5256x; 1.0346x over previous
//
#include <hip/hip_runtime.h>

#define NODES_MAX 100000
#define EDGES_MAX 1600000
#define BN 256                                   // nodes per bucket (pow2)
#define NBUCK ((NODES_MAX + BN - 1) / BN)        // 391
#define B_PART 256                               // partition blocks (fixed)
#define SCAN_CHUNK 1024

// fp32 scratch (r/h tables): r1:0(32) h1:N*32(32) r2:N*64(48) h2:N*112(48)
__device__ float g_ws[(size_t)NODES_MAX * 160];
// bf16 t-tables: t1:0(32/node) t2:N*32(48/node) t3:N*80(16/node)
__device__ unsigned short g_tb[(size_t)NODES_MAX * 96];
__device__ int g_rowptr[NODES_MAX + 1];
__device__ int g_csr[EDGES_MAX];            // src ids grouped by dst
__device__ unsigned g_be[EDGES_MAX];        // bucket-ordered packed (src<<8)|local_dst
__device__ int g_mat[NBUCK * B_PART];       // per-(bucket,block) counts -> offsets
__device__ int g_boff[NBUCK + 1];           // bucket base offsets
__device__ int g_bsum[(NBUCK * B_PART + SCAN_CHUNK - 1) / SCAN_CHUNK + 1];

__device__ __forceinline__ unsigned short f2bf(float f) {
    union { float f; unsigned u; } c; c.f = f;
    unsigned r = (c.u + 0x7FFFu + ((c.u >> 16) & 1u)) >> 16;
    return (unsigned short)r;
}
__device__ __forceinline__ float bflo(unsigned u) {
    union { unsigned u; float f; } c; c.u = u << 16; return c.f;
}
__device__ __forceinline__ float bfhi(unsigned u) {
    union { unsigned u; float f; } c; c.u = u & 0xFFFF0000u; return c.f;
}

// ---------------- CSR build (radix partition, no global atomics) ----------------
__global__ __launch_bounds__(1024) void k_bcount(const int* __restrict__ edge, int E,
                                                 int nbuck, int chunk) {
    __shared__ int h[NBUCK];
    for (int i = threadIdx.x; i < nbuck; i += 1024) h[i] = 0;
    __syncthreads();
    const int lo = blockIdx.x * chunk, hi = min(E, lo + chunk);
    for (int e = lo + threadIdx.x; e < hi; e += 1024)
        atomicAdd(&h[edge[E + e] >> 8], 1);
    __syncthreads();
    for (int k = threadIdx.x; k < nbuck; k += 1024)
        g_mat[k * B_PART + blockIdx.x] = h[k];
}

__global__ __launch_bounds__(256) void k_scan_local(int M) {
    __shared__ int ssum[256];
    const int tid = threadIdx.x;
    const int base = blockIdx.x * SCAN_CHUNK + tid * 4;
    int v0 = (base + 0 < M) ? g_mat[base + 0] : 0;
    int v1 = (base + 1 < M) ? g_mat[base + 1] : 0;
    int v2 = (base + 2 < M) ? g_mat[base + 2] : 0;
    int v3 = (base + 3 < M) ? g_mat[base + 3] : 0;
    int s = v0 + v1 + v2 + v3;
    ssum[tid] = s;
    __syncthreads();
    for (int off = 1; off < 256; off <<= 1) {
        int v = (tid >= off) ? ssum[tid - off] : 0;
        __syncthreads();
        ssum[tid] += v;
        __syncthreads();
    }
    int run = ssum[tid] - s;
    if (base + 0 < M) g_mat[base + 0] = run;
    run += v0;
    if (base + 1 < M) g_mat[base + 1] = run;
    run += v1;
    if (base + 2 < M) g_mat[base + 2] = run;
    run += v2;
    if (base + 3 < M) g_mat[base + 3] = run;
    if (tid == 255) g_bsum[blockIdx.x] = ssum[255];
}

__global__ __launch_bounds__(1024) void k_scan_bsums(int nb) {
    __shared__ int ssum[1024];
    const int tid = threadIdx.x;
    int s = (tid < nb) ? g_bsum[tid] : 0;
    ssum[tid] = s;
    __syncthreads();
    for (int off = 1; off < 1024; off <<= 1) {
        int v = (tid >= off) ? ssum[tid - off] : 0;
        __syncthreads();
        ssum[tid] += v;
        __syncthreads();
    }
    if (tid < nb) g_bsum[tid] = ssum[tid] - s;
}

__global__ __launch_bounds__(256) void k_scan_add(int M, int nbuck, int E) {
    int i = blockIdx.x * 256 + threadIdx.x;
    if (i < M) {
        int v = g_mat[i] + g_bsum[i / SCAN_CHUNK];
        g_mat[i] = v;
        if ((i & (B_PART - 1)) == 0) g_boff[i / B_PART] = v;  // bucket base
    }
    if (i == 0) g_boff[nbuck] = E;
}

__global__ __launch_bounds__(1024) void k_bpart(const int* __restrict__ edge, int E,
                                                int nbuck, int chunk) {
    __shared__ int cur[NBUCK];
    for (int k = threadIdx.x; k < nbuck; k += 1024)
        cur[k] = g_mat[k * B_PART + blockIdx.x];
    __syncthreads();
    const int lo = blockIdx.x * chunk, hi = min(E, lo + chunk);
    for (int e = lo + threadIdx.x; e < hi; e += 1024) {
        int s = edge[e], d = edge[E + e];
        int pos = atomicAdd(&cur[d >> 8], 1);
        g_be[pos] = ((unsigned)s << 8) | (unsigned)(d & (BN - 1));
    }
}

__global__ __launch_bounds__(BN) void k_csr(int N, int E) {
    const int b = blockIdx.x;
    const int nlo = b * BN;
    const int ebase = g_boff[b], eend = g_boff[b + 1];
    __shared__ int cnt[BN];
    __shared__ int pfx[BN];
    const int tid = threadIdx.x;
    cnt[tid] = 0;
    __syncthreads();
    for (int e = ebase + tid; e < eend; e += BN)
        atomicAdd(&cnt[g_be[e] & (BN - 1)], 1);
    __syncthreads();
    int v = cnt[tid];
    pfx[tid] = v;
    __syncthreads();
    for (int off = 1; off < BN; off <<= 1) {
        int t = (tid >= off) ? pfx[tid - off] : 0;
        __syncthreads();
        pfx[tid] += t;
        __syncthreads();
    }
    int excl = pfx[tid] - v;
    int n = nlo + tid;
    if (n < N) g_rowptr[n] = ebase + excl;
    if (b == 0 && tid == 0) g_rowptr[N] = E;
    cnt[tid] = excl;  // reuse as cursor
    __syncthreads();
    for (int e = ebase + tid; e < eend; e += BN) {
        unsigned pv = g_be[e];
        int pos = atomicAdd(&cnt[pv & (BN - 1)], 1);
        g_csr[ebase + pos] = (int)(pv >> 8);
    }
}

// ---------------- gathers (bf16 rows, fp32 accumulate) ----------------
// h[node] = relu( sum_{in-edges} t_bf16[src] + r[node] );  L = F/8 lanes per node
template <int F>
__global__ __launch_bounds__(256) void k_gather_relu(size_t oTB, size_t oR, size_t oH, int N) {
    constexpr int L = F / 8;
    int tid = blockIdx.x * 256 + threadIdx.x;
    int node = tid / L, c = tid % L;
    if (node >= N) return;
    const unsigned short* __restrict__ tb = &g_tb[oTB];
    int start = g_rowptr[node], end = g_rowptr[node + 1];
    float s0 = 0.f, s1 = 0.f, s2 = 0.f, s3 = 0.f, s4 = 0.f, s5 = 0.f, s6 = 0.f, s7 = 0.f;
    for (int j = start; j < end; ++j) {
        int sn = g_csr[j];
        const uint4 v = *(const uint4*)&tb[(size_t)sn * F + c * 8];
        s0 += bflo(v.x); s1 += bfhi(v.x);
        s2 += bflo(v.y); s3 += bfhi(v.y);
        s4 += bflo(v.z); s5 += bfhi(v.z);
        s6 += bflo(v.w); s7 += bfhi(v.w);
    }
    const size_t ro = oR + (size_t)node * F + c * 8;
    const float4 ra = *(const float4*)&g_ws[ro];
    const float4 rb = *(const float4*)&g_ws[ro + 4];
    float4 oa, ob;
    oa.x = fmaxf(s0 + ra.x, 0.f); oa.y = fmaxf(s1 + ra.y, 0.f);
    oa.z = fmaxf(s2 + ra.z, 0.f); oa.w = fmaxf(s3 + ra.w, 0.f);
    ob.x = fmaxf(s4 + rb.x, 0.f); ob.y = fmaxf(s5 + rb.y, 0.f);
    ob.z = fmaxf(s6 + rb.z, 0.f); ob.w = fmaxf(s7 + rb.w, 0.f);
    const size_t ho = oH + (size_t)node * F + c * 8;
    *(float4*)&g_ws[ho] = oa;
    *(float4*)&g_ws[ho + 4] = ob;
}

// out[node] += sum_{in-edges} t3_bf16[src]   (out pre-seeded); F=16, 2 lanes/node
__global__ __launch_bounds__(256) void k_gather_out(size_t oTB, float* __restrict__ out, int N) {
    constexpr int F = 16, L = 2;
    int tid = blockIdx.x * 256 + threadIdx.x;
    int node = tid / L, c = tid % L;
    if (node >= N) return;
    const unsigned short* __restrict__ tb = &g_tb[oTB];
    int start = g_rowptr[node], end = g_rowptr[node + 1];
    float s0 = 0.f, s1 = 0.f, s2 = 0.f, s3 = 0.f, s4 = 0.f, s5 = 0.f, s6 = 0.f, s7 = 0.f;
    for (int j = start; j < end; ++j) {
        int sn = g_csr[j];
        const uint4 v = *(const uint4*)&tb[(size_t)sn * F + c * 8];
        s0 += bflo(v.x); s1 += bfhi(v.x);
        s2 += bflo(v.y); s3 += bfhi(v.y);
        s4 += bflo(v.z); s5 += bfhi(v.z);
        s6 += bflo(v.w); s7 += bfhi(v.w);
    }
    float* op = &out[(size_t)node * F + c * 8];
    float4 oa = *(float4*)op;
    float4 ob = *(float4*)(op + 4);
    oa.x += s0; oa.y += s1; oa.z += s2; oa.w += s3;
    ob.x += s4; ob.y += s5; ob.z += s6; ob.w += s7;
    *(float4*)op = oa;
    *(float4*)(op + 4) = ob;
}

// ---------------- transforms ----------------
__global__ __launch_bounds__(256) void k_l1_transform(
        const float* __restrict__ x, const float* __restrict__ ax,
        const float* __restrict__ Wrel, const float* __restrict__ Wroot,
        const float* __restrict__ b, int N, size_t oTB1, size_t oR1) {
    __shared__ float sWrel[64 * 32];
    __shared__ float sWroot[64 * 32];
    __shared__ float sH[8 * 64];
    const int tid = threadIdx.x;
    for (int i = tid; i < 64 * 32; i += 256) { sWrel[i] = Wrel[i]; sWroot[i] = Wroot[i]; }
    const int n0 = blockIdx.x * 8;
    for (int i = tid; i < 8 * 64; i += 256) {
        int nl = i >> 6, k = i & 63, n = n0 + nl;
        float v = 0.f;
        if (n < N) v = (k < 48) ? x[(size_t)n * 48 + k] : ax[(size_t)n * 16 + (k - 48)];
        sH[i] = v;
    }
    __syncthreads();
    const int nl = tid >> 5, j = tid & 31, n = n0 + nl;
    if (n < N) {
        float at = 0.f, ar = 0.f;
        #pragma unroll
        for (int k = 0; k < 64; ++k) {
            float h = sH[nl * 64 + k];
            at = fmaf(h, sWrel[k * 32 + j], at);
            ar = fmaf(h, sWroot[k * 32 + j], ar);
        }
        g_tb[oTB1 + (size_t)n * 32 + j] = f2bf(at);
        g_ws[oR1 + (size_t)n * 32 + j] = ar + b[j];
    }
}

__global__ __launch_bounds__(384) void k_l2_transform(
        const float* __restrict__ lf,
        const float* __restrict__ Wrel, const float* __restrict__ Wroot,
        const float* __restrict__ b, int N,
        size_t oH1, size_t oTB2, size_t oR2) {
    __shared__ float sWrel[48 * 48];
    __shared__ float sWroot[48 * 48];
    __shared__ float sH[8 * 48];
    const int tid = threadIdx.x;
    for (int i = tid; i < 48 * 48; i += 384) { sWrel[i] = Wrel[i]; sWroot[i] = Wroot[i]; }
    const int n0 = blockIdx.x * 8;
    {
        int nl = tid / 48, k = tid % 48, n = n0 + nl;  // 384 == 8*48
        float v = 0.f;
        if (n < N) {
            v = (k < 32) ? g_ws[oH1 + (size_t)n * 32 + k]
                         : lf[(size_t)n * 16 + (k - 32)];
        }
        sH[tid] = v;
    }
    __syncthreads();
    const int nl = tid / 48, j = tid % 48, n = n0 + nl;
    if (n < N) {
        float at = 0.f, ar = 0.f;
        #pragma unroll
        for (int k = 0; k < 48; ++k) {
            float h = sH[nl * 48 + k];
            at = fmaf(h, sWrel[k * 48 + j], at);
            ar = fmaf(h, sWroot[k * 48 + j], ar);
        }
        g_tb[oTB2 + (size_t)n * 48 + j] = f2bf(at);
        g_ws[oR2 + (size_t)n * 48 + j] = ar + b[j];
    }
}

__global__ __launch_bounds__(256) void k_l3_transform(
        const float* __restrict__ ax,
        const float* __restrict__ Wrel, const float* __restrict__ Wroot,
        const float* __restrict__ b, int N,
        size_t oH2, size_t oTB3, float* __restrict__ out) {
    __shared__ float sWrel[48 * 16];
    __shared__ float sWroot[48 * 16];
    __shared__ float sH[16 * 48];
    const int tid = threadIdx.x;
    for (int i = tid; i < 48 * 16; i += 256) { sWrel[i] = Wrel[i]; sWroot[i] = Wroot[i]; }
    const int n0 = blockIdx.x * 16;
    for (int i = tid; i < 16 * 48; i += 256) {
        int nl = i / 48, k = i % 48, n = n0 + nl;
        sH[i] = (n < N) ? g_ws[oH2 + (size_t)n * 48 + k] : 0.f;
    }
    __syncthreads();
    const int nl = tid >> 4, j = tid & 15, n = n0 + nl;
    if (n < N) {
        float at = 0.f, ar = 0.f;
        #pragma unroll
        for (int k = 0; k < 48; ++k) {
            float h = sH[nl * 48 + k];
            at = fmaf(h, sWrel[k * 16 + j], at);
            ar = fmaf(h, sWroot[k * 16 + j], ar);
        }
        g_tb[oTB3 + (size_t)n * 16 + j] = f2bf(at);
        out[(size_t)n * 16 + j] = ar + b[j] + ax[(size_t)n * 16 + j];
    }
}

extern "C" void kernel_launch(void* const* d_in, const int* in_sizes, int n_in,
                              void* d_out, int out_size, void* d_ws, size_t ws_size,
                              hipStream_t stream) {
    const float* x     = (const float*)d_in[0];
    const int*   edge  = (const int*)d_in[1];
    const float* ax    = (const float*)d_in[2];
    const float* lf    = (const float*)d_in[3];
    const float* W1rel = (const float*)d_in[4];
    const float* b1    = (const float*)d_in[5];
    const float* W1root= (const float*)d_in[6];
    const float* W2rel = (const float*)d_in[7];
    const float* b2    = (const float*)d_in[8];
    const float* W2root= (const float*)d_in[9];
    const float* W3rel = (const float*)d_in[10];
    const float* b3    = (const float*)d_in[11];
    const float* W3root= (const float*)d_in[12];
    float* out = (float*)d_out;

    const int N = in_sizes[0] / 48;
    const int E = in_sizes[1] / 2;
    const int nbuck = (N + BN - 1) / BN;
    const int chunk = (E + B_PART - 1) / B_PART;
    const int M = nbuck * B_PART;
    const int nb = (M + SCAN_CHUNK - 1) / SCAN_CHUNK;

    // fp32 tables
    const size_t oR1 = 0;
    const size_t oH1 = (size_t)N * 32;
    const size_t oR2 = (size_t)N * 64;
    const size_t oH2 = (size_t)N * 112;
    // bf16 t-tables
    const size_t oTB1 = 0;
    const size_t oTB2 = (size_t)N * 32;
    const size_t oTB3 = (size_t)N * 80;

    // CSR build (radix partition, no global atomics)
    k_bcount<<<B_PART, 1024, 0, stream>>>(edge, E, nbuck, chunk);
    k_scan_local<<<nb, 256, 0, stream>>>(M);
    k_scan_bsums<<<1, 1024, 0, stream>>>(nb);
    k_scan_add<<<(M + 255) / 256, 256, 0, stream>>>(M, nbuck, E);
    k_bpart<<<B_PART, 1024, 0, stream>>>(edge, E, nbuck, chunk);
    k_csr<<<nbuck, BN, 0, stream>>>(N, E);

    // Layer 1 (L=4 lanes/node)
    k_l1_transform<<<(N + 7) / 8, 256, 0, stream>>>(x, ax, W1rel, W1root, b1, N, oTB1, oR1);
    k_gather_relu<32><<<(unsigned)(((size_t)N * 4 + 255) / 256), 256, 0, stream>>>(oTB1, oR1, oH1, N);
    // Layer 2 (L=6 lanes/node)
    k_l2_transform<<<(N + 7) / 8, 384, 0, stream>>>(lf, W2rel, W2root, b2, N, oH1, oTB2, oR2);
    k_gather_relu<48><<<(unsigned)(((size_t)N * 6 + 255) / 256), 256, 0, stream>>>(oTB2, oR2, oH2, N);
    // Layer 3 (L=2 lanes/node)
    k_l3_transform<<<(N + 15) / 16, 256, 0, stream>>>(ax, W3rel, W3root, b3, N, oH2, oTB3, out);
    k_gather_out<<<(unsigned)(((size_t)N * 2 + 255) / 256), 256, 0, stream>>>(oTB3, out, N);
}